// Round 8
// baseline (489.585 us; speedup 1.0000x reference)
//
#include <hip/hip_runtime.h>

#define BATCH 16
#define TILE 2048  // scan tile: 256 threads x 8 values

__device__ __forceinline__ float fast_tanh(float v) {
    float a = fabsf(v);
    float e = __expf(2.0f * a);
    float t = 1.0f - 2.0f / (e + 1.0f);
    return copysignf(t, v);
}

__device__ __forceinline__ float blend(float lin, float alpha) {
    return lin + alpha * (fast_tanh(lin) - lin);
}

// xT[n*B+b] = x[b*N+n]
__global__ __launch_bounds__(256) void k_transpose(const float* __restrict__ x,
                                                   float* __restrict__ xT, int N) {
    int n = blockIdx.x * blockDim.x + threadIdx.x;
    if (n >= N) return;
    float v[BATCH];
#pragma unroll
    for (int b = 0; b < BATCH; ++b) v[b] = x[(size_t)b * N + n];
    float4* dst = (float4*)(xT + (size_t)n * BATCH);
#pragma unroll
    for (int i = 0; i < BATCH / 4; ++i)
        dst[i] = make_float4(v[4 * i], v[4 * i + 1], v[4 * i + 2], v[4 * i + 3]);
}

// ---- partitioned histogram: block p owns histP[p][0..N), workgroup-scope atomics
// (only this block touches the slice; end-of-kernel release publishes it)
__global__ __launch_bounds__(256) void k_hist_part(const int* __restrict__ dst,
                                                   int* __restrict__ histP,
                                                   int* __restrict__ rank,
                                                   int E, int EPP, int N) {
    int p = blockIdx.x;
    int* hist = histP + (size_t)p * N;
    int beg = p * EPP;
    int end = min(E, beg + EPP);
    for (int base = beg + (int)threadIdx.x * 4; base < end; base += blockDim.x * 4) {
        if (base + 3 < end) {
            int4 d = *(const int4*)(dst + base);
            int r0 = __hip_atomic_fetch_add(&hist[d.x], 1, __ATOMIC_RELAXED, __HIP_MEMORY_SCOPE_WORKGROUP);
            int r1 = __hip_atomic_fetch_add(&hist[d.y], 1, __ATOMIC_RELAXED, __HIP_MEMORY_SCOPE_WORKGROUP);
            int r2 = __hip_atomic_fetch_add(&hist[d.z], 1, __ATOMIC_RELAXED, __HIP_MEMORY_SCOPE_WORKGROUP);
            int r3 = __hip_atomic_fetch_add(&hist[d.w], 1, __ATOMIC_RELAXED, __HIP_MEMORY_SCOPE_WORKGROUP);
            *(int4*)(rank + base) = make_int4(r0, r1, r2, r3);
        } else {
            for (int e = base; e < end; ++e)
                rank[e] = __hip_atomic_fetch_add(&hist[dst[e]], 1, __ATOMIC_RELAXED, __HIP_MEMORY_SCOPE_WORKGROUP);
        }
    }
}

// column scan: histP[p][n] <- sum_{q<p} histP[q][n]; counts[n] = total. Coalesced.
__global__ __launch_bounds__(256) void k_colscan(int* __restrict__ histP,
                                                 int* __restrict__ counts, int N, int P) {
    int n = blockIdx.x * blockDim.x + threadIdx.x;
    if (n >= N) return;
    int run = 0;
    for (int p = 0; p < P; ++p) {
        size_t i = (size_t)p * N + n;
        int t = histP[i];
        histP[i] = run;
        run += t;
    }
    counts[n] = run;
}

// single-pass variant: counts + rank via device-scope atomics (fallback)
__global__ __launch_bounds__(256) void k_hist_rank(const int* __restrict__ dst,
                                                   int* __restrict__ counts,
                                                   int* __restrict__ rank, int E) {
    int i = blockIdx.x * blockDim.x + threadIdx.x;
    int base = i * 4;
    if (base + 3 < E) {
        int4 d = *(const int4*)(dst + base);
        int r0 = atomicAdd(&counts[d.x], 1);
        int r1 = atomicAdd(&counts[d.y], 1);
        int r2 = atomicAdd(&counts[d.z], 1);
        int r3 = atomicAdd(&counts[d.w], 1);
        *(int4*)(rank + base) = make_int4(r0, r1, r2, r3);
    } else {
        for (int e = base; e < E; ++e) rank[e] = atomicAdd(&counts[dst[e]], 1);
    }
}

// per-tile exclusive scan; tile totals to tileSums
__global__ __launch_bounds__(256) void k_scan_tiles(const int* __restrict__ counts,
                                                    int* __restrict__ offsets,
                                                    int* __restrict__ tileSums, int N) {
    __shared__ int sdata[256];
    int t = threadIdx.x;
    int base = blockIdx.x * TILE + t * 8;
    int v[8];
    int s = 0;
#pragma unroll
    for (int i = 0; i < 8; ++i) {
        v[i] = (base + i < N) ? counts[base + i] : 0;
        s += v[i];
    }
    sdata[t] = s;
    __syncthreads();
    for (int off = 1; off < 256; off <<= 1) {
        int add = 0;
        if (t >= off) add = sdata[t - off];
        __syncthreads();
        sdata[t] += add;
        __syncthreads();
    }
    int run = sdata[t] - s;
#pragma unroll
    for (int i = 0; i < 8; ++i) {
        if (base + i < N) offsets[base + i] = run;
        run += v[i];
    }
    if (t == 255) tileSums[blockIdx.x] = sdata[255];
}

__global__ __launch_bounds__(256) void k_scan_sums(int* __restrict__ tileSums,
                                                   int* __restrict__ offsets,
                                                   int nTiles, int N, int E) {
    __shared__ int sh[256];
    int t = threadIdx.x;
    int v = (t < nTiles) ? tileSums[t] : 0;
    sh[t] = v;
    __syncthreads();
    for (int off = 1; off < 256; off <<= 1) {
        int add = 0;
        if (t >= off) add = sh[t - off];
        __syncthreads();
        sh[t] += add;
        __syncthreads();
    }
    if (t < nTiles) tileSums[t] = sh[t] - v;  // exclusive
    if (t == 0) offsets[N] = E;
}

__global__ __launch_bounds__(256) void k_add(int* __restrict__ offsets,
                                             const int* __restrict__ tileSums, int N) {
    int i = blockIdx.x * blockDim.x + threadIdx.x;
    if (i >= N) return;
    offsets[i] += tileSums[i / TILE];
}

// scatter for the partitioned path: slot = offsets[d] + histP[e/EPP][d] + rank[e]
__global__ __launch_bounds__(256) void k_scatter_part(const int* __restrict__ src,
                                                      const int* __restrict__ dst,
                                                      const float* __restrict__ ea,
                                                      const float* __restrict__ ew,
                                                      const float* __restrict__ eb,
                                                      const int* __restrict__ rank,
                                                      const int* __restrict__ offsets,
                                                      const int* __restrict__ histP,
                                                      float4* __restrict__ sorted,
                                                      int E, int EPP, int N) {
    int i = blockIdx.x * blockDim.x + threadIdx.x;
    int base = i * 4;
    if (base >= E) return;
    const int* hb = histP + (size_t)(base / EPP) * N;  // EPP%4==0 -> all 4 same partition
    if (base + 3 < E) {
        int4 s = *(const int4*)(src + base);
        int4 d = *(const int4*)(dst + base);
        int4 r = *(const int4*)(rank + base);
        float4 a = *(const float4*)(ea + base);
        float4 w = *(const float4*)(ew + base);
        float4 b = *(const float4*)(eb + base);
        sorted[offsets[d.x] + hb[d.x] + r.x] = make_float4(__int_as_float(s.x), a.x, w.x, b.x);
        sorted[offsets[d.y] + hb[d.y] + r.y] = make_float4(__int_as_float(s.y), a.y, w.y, b.y);
        sorted[offsets[d.z] + hb[d.z] + r.z] = make_float4(__int_as_float(s.z), a.z, w.z, b.z);
        sorted[offsets[d.w] + hb[d.w] + r.w] = make_float4(__int_as_float(s.w), a.w, w.w, b.w);
    } else {
        for (int e = base; e < E; ++e)
            sorted[offsets[dst[e]] + hb[dst[e]] + rank[e]] =
                make_float4(__int_as_float(src[e]), ea[e], ew[e], eb[e]);
    }
}

// scatter for the single-hist fallback path
__global__ __launch_bounds__(256) void k_scatter_rank(const int* __restrict__ src,
                                                      const int* __restrict__ dst,
                                                      const float* __restrict__ ea,
                                                      const float* __restrict__ ew,
                                                      const float* __restrict__ eb,
                                                      const int* __restrict__ rank,
                                                      const int* __restrict__ offsets,
                                                      float4* __restrict__ sorted, int E) {
    int i = blockIdx.x * blockDim.x + threadIdx.x;
    int base = i * 4;
    if (base + 3 < E) {
        int4 s = *(const int4*)(src + base);
        int4 d = *(const int4*)(dst + base);
        int4 r = *(const int4*)(rank + base);
        float4 a = *(const float4*)(ea + base);
        float4 w = *(const float4*)(ew + base);
        float4 b = *(const float4*)(eb + base);
        sorted[offsets[d.x] + r.x] = make_float4(__int_as_float(s.x), a.x, w.x, b.x);
        sorted[offsets[d.y] + r.y] = make_float4(__int_as_float(s.y), a.y, w.y, b.y);
        sorted[offsets[d.z] + r.z] = make_float4(__int_as_float(s.z), a.z, w.z, b.z);
        sorted[offsets[d.w] + r.w] = make_float4(__int_as_float(s.w), a.w, w.w, b.w);
    } else {
        for (int e = base; e < E; ++e)
            sorted[offsets[dst[e]] + rank[e]] =
                make_float4(__int_as_float(src[e]), ea[e], ew[e], eb[e]);
    }
}

// 4 lanes per node: lane j owns batch-quadrant j (float4). No atomics.
__global__ __launch_bounds__(256) void k_gather(const float4* __restrict__ sorted,
                                                const int* __restrict__ offsets,
                                                const float* __restrict__ xT,
                                                const float* __restrict__ na,
                                                const float* __restrict__ nw,
                                                const float* __restrict__ nb,
                                                float* __restrict__ out, int N) {
    int t = blockIdx.x * blockDim.x + threadIdx.x;
    int n = t >> 2;
    int j = t & 3;
    if (n >= N) return;
    int beg = offsets[n], end = offsets[n + 1];
    float4 acc = make_float4(0.f, 0.f, 0.f, 0.f);
    for (int r = beg; r < end; ++r) {
        float4 pl = sorted[r];  // {src, alpha, w, b} broadcast to the 4 lanes
        int s = __float_as_int(pl.x);
        float4 xv = *(const float4*)(xT + (size_t)s * BATCH + j * 4);
        acc.x += blend(pl.z * xv.x + pl.w, pl.y);
        acc.y += blend(pl.z * xv.y + pl.w, pl.y);
        acc.z += blend(pl.z * xv.z + pl.w, pl.y);
        acc.w += blend(pl.z * xv.w + pl.w, pl.y);
    }
    float a = na[n], w = nw[n], bb = nb[n];
    out[(size_t)(4 * j + 0) * N + n] = blend(w * acc.x + bb, a);
    out[(size_t)(4 * j + 1) * N + n] = blend(w * acc.y + bb, a);
    out[(size_t)(4 * j + 2) * N + n] = blend(w * acc.z + bb, a);
    out[(size_t)(4 * j + 3) * N + n] = blend(w * acc.w + bb, a);
}

// ---------------- fallback: direct atomic path ----------------

__global__ __launch_bounds__(256) void k_edge_direct(const int* __restrict__ src,
                                                     const int* __restrict__ dst,
                                                     const float* __restrict__ ea,
                                                     const float* __restrict__ ew,
                                                     const float* __restrict__ eb,
                                                     const float* __restrict__ x,
                                                     float* __restrict__ out, int N, int E) {
    int e = blockIdx.x * blockDim.x + threadIdx.x;
    if (e >= E) return;
    int s = src[e], d = dst[e];
    float a = ea[e], w = ew[e], bb = eb[e];
#pragma unroll
    for (int b = 0; b < BATCH; ++b) {
        float xv = x[(size_t)b * N + s];
        unsafeAtomicAdd(out + (size_t)b * N + d, blend(w * xv + bb, a));
    }
}

__global__ __launch_bounds__(256) void k_node_inplace(const float* __restrict__ na,
                                                      const float* __restrict__ nw,
                                                      const float* __restrict__ nb,
                                                      float* __restrict__ out, int N) {
    int n = blockIdx.x * blockDim.x + threadIdx.x;
    if (n >= N) return;
    float a = na[n], w = nw[n], bb = nb[n];
#pragma unroll
    for (int b = 0; b < BATCH; ++b) {
        size_t idx = (size_t)b * N + n;
        out[idx] = blend(w * out[idx] + bb, a);
    }
}

extern "C" void kernel_launch(void* const* d_in, const int* in_sizes, int n_in,
                              void* d_out, int out_size, void* d_ws, size_t ws_size,
                              hipStream_t stream) {
    const float* x   = (const float*)d_in[0];
    const int*   src = (const int*)  d_in[1];
    const int*   dst = (const int*)  d_in[2];
    const float* ea  = (const float*)d_in[3];
    const float* ew  = (const float*)d_in[4];
    const float* eb  = (const float*)d_in[5];
    const float* na  = (const float*)d_in[6];
    const float* nw  = (const float*)d_in[7];
    const float* nb  = (const float*)d_in[8];
    float* out = (float*)d_out;

    const int E = in_sizes[1];
    const int N = in_sizes[6];
    const int bt = 256;
    const int nTiles = (N + TILE - 1) / TILE;
    const int gE4 = ((E + 3) / 4 + bt - 1) / bt;

    // workspace layout
    float*  xT      = (float*)d_ws;                       // N*16 floats
    float4* sorted  = (float4*)(xT + (size_t)N * BATCH);  // E float4
    int*    rank    = (int*)(sorted + (size_t)E);         // E ints
    int*    histP   = rank + E;                           // P*N ints (part path)
    // counts/offsets/tileSums placed after histP (P runtime-chosen below)

    size_t base_need = (size_t)N * BATCH * sizeof(float) + (size_t)E * sizeof(float4) +
                       (size_t)E * sizeof(int) + ((size_t)2 * N + 1 + 256) * sizeof(int);

    // pick largest P in {64,32,16} that fits
    int P = 0;
    for (int cand = 64; cand >= 16; cand >>= 1) {
        if (ws_size >= base_need + (size_t)cand * N * sizeof(int)) { P = cand; break; }
    }

    if (P >= 16 && nTiles <= 256) {
        int*  counts   = histP + (size_t)P * N;
        int*  offsets  = counts + N;
        int*  tileSums = offsets + (N + 1);
        int EPP = (((E + P - 1) / P) + 3) & ~3;  // multiple of 4
        // zero histP + counts in one shot (contiguous)
        hipMemsetAsync(histP, 0, ((size_t)P * N + N) * sizeof(int), stream);
        k_transpose<<<(N + bt - 1) / bt, bt, 0, stream>>>(x, xT, N);
        k_hist_part<<<P, bt, 0, stream>>>(dst, histP, rank, E, EPP, N);
        k_colscan<<<(N + bt - 1) / bt, bt, 0, stream>>>(histP, counts, N, P);
        k_scan_tiles<<<nTiles, 256, 0, stream>>>(counts, offsets, tileSums, N);
        k_scan_sums<<<1, 256, 0, stream>>>(tileSums, offsets, nTiles, N, E);
        k_add<<<(N + bt - 1) / bt, bt, 0, stream>>>(offsets, tileSums, N);
        k_scatter_part<<<gE4, bt, 0, stream>>>(src, dst, ea, ew, eb, rank, offsets, histP,
                                               sorted, E, EPP, N);
        k_gather<<<((size_t)N * 4 + bt - 1) / bt, bt, 0, stream>>>(sorted, offsets, xT,
                                                                   na, nw, nb, out, N);
    } else if (ws_size >= base_need && nTiles <= 256) {
        int*  counts   = rank + E;  // no histP on this path
        int*  offsets  = counts + N;
        int*  tileSums = offsets + (N + 1);
        hipMemsetAsync(counts, 0, (size_t)N * sizeof(int), stream);
        k_transpose<<<(N + bt - 1) / bt, bt, 0, stream>>>(x, xT, N);
        k_hist_rank<<<gE4, bt, 0, stream>>>(dst, counts, rank, E);
        k_scan_tiles<<<nTiles, 256, 0, stream>>>(counts, offsets, tileSums, N);
        k_scan_sums<<<1, 256, 0, stream>>>(tileSums, offsets, nTiles, N, E);
        k_add<<<(N + bt - 1) / bt, bt, 0, stream>>>(offsets, tileSums, N);
        k_scatter_rank<<<gE4, bt, 0, stream>>>(src, dst, ea, ew, eb, rank, offsets, sorted, E);
        k_gather<<<((size_t)N * 4 + bt - 1) / bt, bt, 0, stream>>>(sorted, offsets, xT,
                                                                   na, nw, nb, out, N);
    } else {
        hipMemsetAsync(d_out, 0, (size_t)out_size * sizeof(float), stream);
        k_edge_direct<<<(E + bt - 1) / bt, bt, 0, stream>>>(src, dst, ea, ew, eb, x, out, N, E);
        k_node_inplace<<<(N + bt - 1) / bt, bt, 0, stream>>>(na, nw, nb, out, N);
    }
}

// Round 9
// 371.102 us; speedup vs baseline: 1.3193x; 1.3193x over previous
//
#include <hip/hip_runtime.h>

#define BATCH 16
#define TILE 2048   // scan tile: 256 threads x 8 values
#define RNG 40000   // nodes per LDS range; 2 packed 16-bit counters per u32 -> 80000 B LDS

__device__ __forceinline__ float fast_tanh(float v) {
    float a = fabsf(v);
    float e = __expf(2.0f * a);
    float t = 1.0f - 2.0f / (e + 1.0f);
    return copysignf(t, v);
}

__device__ __forceinline__ float blend(float lin, float alpha) {
    return lin + alpha * (fast_tanh(lin) - lin);
}

// xT[n*B+b] = x[b*N+n]
__global__ __launch_bounds__(256) void k_transpose(const float* __restrict__ x,
                                                   float* __restrict__ xT, int N) {
    int n = blockIdx.x * blockDim.x + threadIdx.x;
    if (n >= N) return;
    float v[BATCH];
#pragma unroll
    for (int b = 0; b < BATCH; ++b) v[b] = x[(size_t)b * N + n];
    float4* dst = (float4*)(xT + (size_t)n * BATCH);
#pragma unroll
    for (int i = 0; i < BATCH / 4; ++i)
        dst[i] = make_float4(v[4 * i], v[4 * i + 1], v[4 * i + 2], v[4 * i + 3]);
}

// ---- 2D LDS histogram+rank: grid (S, G). Block (s,g): edges of slice s whose dst
// lies in node range [g*RNG,(g+1)*RNG) are ranked via LDS atomics (packed 16-bit).
// Writes per-edge rank (masked) and its dense count row histP[s][range]. ZERO global atomics.
__global__ __launch_bounds__(256) void k_hist_lds(const int* __restrict__ dst,
                                                  int* __restrict__ histP,
                                                  int* __restrict__ rank,
                                                  int E, int EPS, int N) {
    __shared__ unsigned cnt[RNG / 2];
    int s = blockIdx.x;
    int n0 = blockIdx.y * RNG;
    for (int i = threadIdx.x; i < RNG / 2; i += 256) cnt[i] = 0u;
    __syncthreads();
    int beg = s * EPS, end = min(E, beg + EPS);
    for (int base = beg + (int)threadIdx.x * 4; base < end; base += 256 * 4) {
        if (base + 3 < end) {
            int4 d4 = *(const int4*)(dst + base);
            int dd[4] = {d4.x, d4.y, d4.z, d4.w};
#pragma unroll
            for (int k = 0; k < 4; ++k) {
                unsigned r = (unsigned)(dd[k] - n0);
                if (r < (unsigned)RNG) {
                    unsigned sh = (r & 1u) * 16u;
                    unsigned old = atomicAdd(&cnt[r >> 1], 1u << sh);
                    rank[base + k] = (int)((old >> sh) & 0xffffu);
                }
            }
        } else {
            for (int e = base; e < end; ++e) {
                unsigned r = (unsigned)(dst[e] - n0);
                if (r < (unsigned)RNG) {
                    unsigned sh = (r & 1u) * 16u;
                    unsigned old = atomicAdd(&cnt[r >> 1], 1u << sh);
                    rank[e] = (int)((old >> sh) & 0xffffu);
                }
            }
        }
    }
    __syncthreads();
    int* hp = histP + (size_t)s * N;
    for (int i = threadIdx.x; i < RNG; i += 256) {
        int n = n0 + i;
        if (n < N) hp[n] = (int)((cnt[i >> 1] >> ((i & 1) * 16)) & 0xffffu);
    }
}

// column scan: histP[p][n] <- sum_{q<p} histP[q][n]; counts[n] = total. Coalesced.
__global__ __launch_bounds__(256) void k_colscan(int* __restrict__ histP,
                                                 int* __restrict__ counts, int N, int P) {
    int n = blockIdx.x * blockDim.x + threadIdx.x;
    if (n >= N) return;
    int run = 0;
    for (int p = 0; p < P; ++p) {
        size_t i = (size_t)p * N + n;
        int t = histP[i];
        histP[i] = run;
        run += t;
    }
    counts[n] = run;
}

// single-pass variant: counts + rank via device-scope atomics (fallback)
__global__ __launch_bounds__(256) void k_hist_rank(const int* __restrict__ dst,
                                                   int* __restrict__ counts,
                                                   int* __restrict__ rank, int E) {
    int i = blockIdx.x * blockDim.x + threadIdx.x;
    int base = i * 4;
    if (base + 3 < E) {
        int4 d = *(const int4*)(dst + base);
        int r0 = atomicAdd(&counts[d.x], 1);
        int r1 = atomicAdd(&counts[d.y], 1);
        int r2 = atomicAdd(&counts[d.z], 1);
        int r3 = atomicAdd(&counts[d.w], 1);
        *(int4*)(rank + base) = make_int4(r0, r1, r2, r3);
    } else {
        for (int e = base; e < E; ++e) rank[e] = atomicAdd(&counts[dst[e]], 1);
    }
}

// per-tile exclusive scan; tile totals to tileSums
__global__ __launch_bounds__(256) void k_scan_tiles(const int* __restrict__ counts,
                                                    int* __restrict__ offsets,
                                                    int* __restrict__ tileSums, int N) {
    __shared__ int sdata[256];
    int t = threadIdx.x;
    int base = blockIdx.x * TILE + t * 8;
    int v[8];
    int s = 0;
#pragma unroll
    for (int i = 0; i < 8; ++i) {
        v[i] = (base + i < N) ? counts[base + i] : 0;
        s += v[i];
    }
    sdata[t] = s;
    __syncthreads();
    for (int off = 1; off < 256; off <<= 1) {
        int add = 0;
        if (t >= off) add = sdata[t - off];
        __syncthreads();
        sdata[t] += add;
        __syncthreads();
    }
    int run = sdata[t] - s;
#pragma unroll
    for (int i = 0; i < 8; ++i) {
        if (base + i < N) offsets[base + i] = run;
        run += v[i];
    }
    if (t == 255) tileSums[blockIdx.x] = sdata[255];
}

__global__ __launch_bounds__(256) void k_scan_sums(int* __restrict__ tileSums,
                                                   int* __restrict__ offsets,
                                                   int nTiles, int N, int E) {
    __shared__ int sh[256];
    int t = threadIdx.x;
    int v = (t < nTiles) ? tileSums[t] : 0;
    sh[t] = v;
    __syncthreads();
    for (int off = 1; off < 256; off <<= 1) {
        int add = 0;
        if (t >= off) add = sh[t - off];
        __syncthreads();
        sh[t] += add;
        __syncthreads();
    }
    if (t < nTiles) tileSums[t] = sh[t] - v;  // exclusive
    if (t == 0) offsets[N] = E;
}

__global__ __launch_bounds__(256) void k_add(int* __restrict__ offsets,
                                             const int* __restrict__ tileSums, int N) {
    int i = blockIdx.x * blockDim.x + threadIdx.x;
    if (i >= N) return;
    offsets[i] += tileSums[i / TILE];
}

// scatter for the partitioned path: slot = offsets[d] + histP[e/EPS][d] + rank[e]
__global__ __launch_bounds__(256) void k_scatter_part(const int* __restrict__ src,
                                                      const int* __restrict__ dst,
                                                      const float* __restrict__ ea,
                                                      const float* __restrict__ ew,
                                                      const float* __restrict__ eb,
                                                      const int* __restrict__ rank,
                                                      const int* __restrict__ offsets,
                                                      const int* __restrict__ histP,
                                                      float4* __restrict__ sorted,
                                                      int E, int EPS, int N) {
    int i = blockIdx.x * blockDim.x + threadIdx.x;
    int base = i * 4;
    if (base >= E) return;
    const int* hb = histP + (size_t)(base / EPS) * N;  // EPS%4==0 -> all 4 same partition
    if (base + 3 < E) {
        int4 s = *(const int4*)(src + base);
        int4 d = *(const int4*)(dst + base);
        int4 r = *(const int4*)(rank + base);
        float4 a = *(const float4*)(ea + base);
        float4 w = *(const float4*)(ew + base);
        float4 b = *(const float4*)(eb + base);
        sorted[offsets[d.x] + hb[d.x] + r.x] = make_float4(__int_as_float(s.x), a.x, w.x, b.x);
        sorted[offsets[d.y] + hb[d.y] + r.y] = make_float4(__int_as_float(s.y), a.y, w.y, b.y);
        sorted[offsets[d.z] + hb[d.z] + r.z] = make_float4(__int_as_float(s.z), a.z, w.z, b.z);
        sorted[offsets[d.w] + hb[d.w] + r.w] = make_float4(__int_as_float(s.w), a.w, w.w, b.w);
    } else {
        for (int e = base; e < E; ++e)
            sorted[offsets[dst[e]] + hb[dst[e]] + rank[e]] =
                make_float4(__int_as_float(src[e]), ea[e], ew[e], eb[e]);
    }
}

// scatter for the single-hist fallback path
__global__ __launch_bounds__(256) void k_scatter_rank(const int* __restrict__ src,
                                                      const int* __restrict__ dst,
                                                      const float* __restrict__ ea,
                                                      const float* __restrict__ ew,
                                                      const float* __restrict__ eb,
                                                      const int* __restrict__ rank,
                                                      const int* __restrict__ offsets,
                                                      float4* __restrict__ sorted, int E) {
    int i = blockIdx.x * blockDim.x + threadIdx.x;
    int base = i * 4;
    if (base + 3 < E) {
        int4 s = *(const int4*)(src + base);
        int4 d = *(const int4*)(dst + base);
        int4 r = *(const int4*)(rank + base);
        float4 a = *(const float4*)(ea + base);
        float4 w = *(const float4*)(ew + base);
        float4 b = *(const float4*)(eb + base);
        sorted[offsets[d.x] + r.x] = make_float4(__int_as_float(s.x), a.x, w.x, b.x);
        sorted[offsets[d.y] + r.y] = make_float4(__int_as_float(s.y), a.y, w.y, b.y);
        sorted[offsets[d.z] + r.z] = make_float4(__int_as_float(s.z), a.z, w.z, b.z);
        sorted[offsets[d.w] + r.w] = make_float4(__int_as_float(s.w), a.w, w.w, b.w);
    } else {
        for (int e = base; e < E; ++e)
            sorted[offsets[dst[e]] + rank[e]] =
                make_float4(__int_as_float(src[e]), ea[e], ew[e], eb[e]);
    }
}

// 4 lanes per node: lane j owns batch-quadrant j (float4). No atomics.
__global__ __launch_bounds__(256) void k_gather(const float4* __restrict__ sorted,
                                                const int* __restrict__ offsets,
                                                const float* __restrict__ xT,
                                                const float* __restrict__ na,
                                                const float* __restrict__ nw,
                                                const float* __restrict__ nb,
                                                float* __restrict__ out, int N) {
    int t = blockIdx.x * blockDim.x + threadIdx.x;
    int n = t >> 2;
    int j = t & 3;
    if (n >= N) return;
    int beg = offsets[n], end = offsets[n + 1];
    float4 acc = make_float4(0.f, 0.f, 0.f, 0.f);
    for (int r = beg; r < end; ++r) {
        float4 pl = sorted[r];  // {src, alpha, w, b} broadcast to the 4 lanes
        int s = __float_as_int(pl.x);
        float4 xv = *(const float4*)(xT + (size_t)s * BATCH + j * 4);
        acc.x += blend(pl.z * xv.x + pl.w, pl.y);
        acc.y += blend(pl.z * xv.y + pl.w, pl.y);
        acc.z += blend(pl.z * xv.z + pl.w, pl.y);
        acc.w += blend(pl.z * xv.w + pl.w, pl.y);
    }
    float a = na[n], w = nw[n], bb = nb[n];
    out[(size_t)(4 * j + 0) * N + n] = blend(w * acc.x + bb, a);
    out[(size_t)(4 * j + 1) * N + n] = blend(w * acc.y + bb, a);
    out[(size_t)(4 * j + 2) * N + n] = blend(w * acc.z + bb, a);
    out[(size_t)(4 * j + 3) * N + n] = blend(w * acc.w + bb, a);
}

// ---------------- fallback: direct atomic path ----------------

__global__ __launch_bounds__(256) void k_edge_direct(const int* __restrict__ src,
                                                     const int* __restrict__ dst,
                                                     const float* __restrict__ ea,
                                                     const float* __restrict__ ew,
                                                     const float* __restrict__ eb,
                                                     const float* __restrict__ x,
                                                     float* __restrict__ out, int N, int E) {
    int e = blockIdx.x * blockDim.x + threadIdx.x;
    if (e >= E) return;
    int s = src[e], d = dst[e];
    float a = ea[e], w = ew[e], bb = eb[e];
#pragma unroll
    for (int b = 0; b < BATCH; ++b) {
        float xv = x[(size_t)b * N + s];
        unsafeAtomicAdd(out + (size_t)b * N + d, blend(w * xv + bb, a));
    }
}

__global__ __launch_bounds__(256) void k_node_inplace(const float* __restrict__ na,
                                                      const float* __restrict__ nw,
                                                      const float* __restrict__ nb,
                                                      float* __restrict__ out, int N) {
    int n = blockIdx.x * blockDim.x + threadIdx.x;
    if (n >= N) return;
    float a = na[n], w = nw[n], bb = nb[n];
#pragma unroll
    for (int b = 0; b < BATCH; ++b) {
        size_t idx = (size_t)b * N + n;
        out[idx] = blend(w * out[idx] + bb, a);
    }
}

extern "C" void kernel_launch(void* const* d_in, const int* in_sizes, int n_in,
                              void* d_out, int out_size, void* d_ws, size_t ws_size,
                              hipStream_t stream) {
    const float* x   = (const float*)d_in[0];
    const int*   src = (const int*)  d_in[1];
    const int*   dst = (const int*)  d_in[2];
    const float* ea  = (const float*)d_in[3];
    const float* ew  = (const float*)d_in[4];
    const float* eb  = (const float*)d_in[5];
    const float* na  = (const float*)d_in[6];
    const float* nw  = (const float*)d_in[7];
    const float* nb  = (const float*)d_in[8];
    float* out = (float*)d_out;

    const int E = in_sizes[1];
    const int N = in_sizes[6];
    const int bt = 256;
    const int nTiles = (N + TILE - 1) / TILE;
    const int gE4 = ((E + 3) / 4 + bt - 1) / bt;
    const int G = (N + RNG - 1) / RNG;  // node ranges (3 for N=100K)

    // workspace layout
    float*  xT      = (float*)d_ws;                       // N*16 floats
    float4* sorted  = (float4*)(xT + (size_t)N * BATCH);  // E float4
    int*    rank    = (int*)(sorted + (size_t)E);         // E ints
    int*    histP   = rank + E;                           // S*N ints (LDS-hist path)

    size_t base_need = (size_t)N * BATCH * sizeof(float) + (size_t)E * sizeof(float4) +
                       (size_t)E * sizeof(int) + ((size_t)2 * N + 1 + 256) * sizeof(int);

    // pick largest slice count S that fits (tradeoff: hist parallelism vs colscan traffic)
    int S = 0;
    for (int cand = 128; cand >= 32; cand -= 32) {
        if (ws_size >= base_need + (size_t)cand * N * sizeof(int)) { S = cand; break; }
    }

    if (S >= 32 && nTiles <= 256 && G <= 64) {
        int*  counts   = histP + (size_t)S * N;
        int*  offsets  = counts + N;
        int*  tileSums = offsets + (N + 1);
        int EPS = (((E + S - 1) / S) + 3) & ~3;  // slice size, multiple of 4
        // NOTE: no memset needed — k_hist_lds writes every histP[s][n] densely.
        k_transpose<<<(N + bt - 1) / bt, bt, 0, stream>>>(x, xT, N);
        dim3 gh(S, G);
        k_hist_lds<<<gh, bt, 0, stream>>>(dst, histP, rank, E, EPS, N);
        k_colscan<<<(N + bt - 1) / bt, bt, 0, stream>>>(histP, counts, N, S);
        k_scan_tiles<<<nTiles, 256, 0, stream>>>(counts, offsets, tileSums, N);
        k_scan_sums<<<1, 256, 0, stream>>>(tileSums, offsets, nTiles, N, E);
        k_add<<<(N + bt - 1) / bt, bt, 0, stream>>>(offsets, tileSums, N);
        k_scatter_part<<<gE4, bt, 0, stream>>>(src, dst, ea, ew, eb, rank, offsets, histP,
                                               sorted, E, EPS, N);
        k_gather<<<((size_t)N * 4 + bt - 1) / bt, bt, 0, stream>>>(sorted, offsets, xT,
                                                                   na, nw, nb, out, N);
    } else if (ws_size >= base_need && nTiles <= 256) {
        int*  counts   = rank + E;  // no histP on this path
        int*  offsets  = counts + N;
        int*  tileSums = offsets + (N + 1);
        hipMemsetAsync(counts, 0, (size_t)N * sizeof(int), stream);
        k_transpose<<<(N + bt - 1) / bt, bt, 0, stream>>>(x, xT, N);
        k_hist_rank<<<gE4, bt, 0, stream>>>(dst, counts, rank, E);
        k_scan_tiles<<<nTiles, 256, 0, stream>>>(counts, offsets, tileSums, N);
        k_scan_sums<<<1, 256, 0, stream>>>(tileSums, offsets, nTiles, N, E);
        k_add<<<(N + bt - 1) / bt, bt, 0, stream>>>(offsets, tileSums, N);
        k_scatter_rank<<<gE4, bt, 0, stream>>>(src, dst, ea, ew, eb, rank, offsets, sorted, E);
        k_gather<<<((size_t)N * 4 + bt - 1) / bt, bt, 0, stream>>>(sorted, offsets, xT,
                                                                   na, nw, nb, out, N);
    } else {
        hipMemsetAsync(d_out, 0, (size_t)out_size * sizeof(float), stream);
        k_edge_direct<<<(E + bt - 1) / bt, bt, 0, stream>>>(src, dst, ea, ew, eb, x, out, N, E);
        k_node_inplace<<<(N + bt - 1) / bt, bt, 0, stream>>>(na, nw, nb, out, N);
    }
}